// Round 14
// baseline (165.954 us; speedup 1.0000x reference)
//
#include <hip/hip_runtime.h>
#include <hip/hip_bf16.h>

#define SEQ 4096
#define HID 768
#define NHEAD 12
#define HDIM 64
#define KVB 128
#define NT (SEQ / KVB)   // 32
#define PBK 64
#define PNT (HID / PBK)  // 12

typedef __attribute__((ext_vector_type(8))) short bf16x8;
typedef __attribute__((ext_vector_type(4))) float f32x4;
typedef __attribute__((ext_vector_type(4))) short s16x4;

static __device__ __forceinline__ short f2bf(float f) {
    unsigned u = __builtin_bit_cast(unsigned, f);
    unsigned r = (u + 0x7fffu + ((u >> 16) & 1u)) >> 16;
    return (short)r;
}
static __device__ __forceinline__ unsigned cvtpk(float lo, float hi) {
    unsigned r;
    asm("v_cvt_pk_bf16_f32 %0, %1, %2" : "=v"(r) : "v"(lo), "v"(hi));
    return r;
}
static __device__ __forceinline__ float max3f(float a, float b, float c) {
    float r;
    asm("v_max3_f32 %0, %1, %2, %3" : "=v"(r) : "v"(a), "v"(b), "v"(c));
    return r;
}
static __device__ __forceinline__ void glds16(const void* g, void* l) {
    __builtin_amdgcn_global_load_lds(
        (const __attribute__((address_space(1))) unsigned*)g,
        (__attribute__((address_space(3))) unsigned*)l, 16, 0, 0);
}

// ---------------------------------------------------------------------------
// fp32 -> bf16 casts
// ---------------------------------------------------------------------------
__global__ __launch_bounds__(256) void cast_bf16_kernel(
    const float* __restrict__ src, short* __restrict__ dst)
{
    const size_t i = (size_t)blockIdx.x * 256 + threadIdx.x;
    const float4* s = reinterpret_cast<const float4*>(src) + i * 2;
    const float4 a = s[0], b = s[1];
    bf16x8 o;
    o[0] = f2bf(a.x); o[1] = f2bf(a.y); o[2] = f2bf(a.z); o[3] = f2bf(a.w);
    o[4] = f2bf(b.x); o[5] = f2bf(b.y); o[6] = f2bf(b.z); o[7] = f2bf(b.w);
    reinterpret_cast<bf16x8*>(dst)[i] = o;
}

__global__ __launch_bounds__(256) void cast_w_kernel(
    const float* __restrict__ Wq, const float* __restrict__ Wk,
    const float* __restrict__ Wv, short* __restrict__ dst)
{
    const int z = blockIdx.y;
    const float* src = (z == 0) ? Wq : ((z == 1) ? Wk : Wv);
    const size_t i = (size_t)blockIdx.x * 256 + threadIdx.x;
    const float4* s = reinterpret_cast<const float4*>(src) + i * 2;
    const float4 a = s[0], b = s[1];
    bf16x8 o;
    o[0] = f2bf(a.x); o[1] = f2bf(a.y); o[2] = f2bf(a.z); o[3] = f2bf(a.w);
    o[4] = f2bf(b.x); o[5] = f2bf(b.y); o[6] = f2bf(b.z); o[7] = f2bf(b.w);
    reinterpret_cast<bf16x8*>(dst + (size_t)z * HID * HID)[i] = o;
}

// ---------------------------------------------------------------------------
// QKV projection, LDS-staged. Tile 128x128, BK=64, dbuf 64KB.
// Q output pre-scaled by 0.125*log2e (folds the softmax scale).
// ---------------------------------------------------------------------------
__global__ __launch_bounds__(256) void qkv_proj_kernel(
    const short* __restrict__ hsb, const short* __restrict__ Wb,
    const float* __restrict__ bq, const float* __restrict__ bk,
    const float* __restrict__ bv,
    short* __restrict__ Qb, short* __restrict__ Kb, short* __restrict__ Vt)
{
    __shared__ __align__(16) char lds[65536];
    const int z = blockIdx.z;
    const float* bias = (z == 0) ? bq : ((z == 1) ? bk : bv);

    const int lane = threadIdx.x & 63;
    const int w    = threadIdx.x >> 6;
    const int lr = lane & 15, hi = lane >> 4;
    const int wi = w >> 1, wj = w & 1;

    const short* Ag; const short* Bg; int ar0, br0;
    if (z < 2) { Ag = Wb + (size_t)z * HID * HID; ar0 = blockIdx.x * 128;
                 Bg = hsb;                        br0 = blockIdx.y * 128; }
    else       { Ag = hsb;                        ar0 = blockIdx.y * 128;
                 Bg = Wb + (size_t)2 * HID * HID; br0 = blockIdx.x * 128; }

    const int rsub = lane >> 3;
    const int c16  = (lane & 7) ^ rsub;

    auto stage = [&](int t, int buf) {
        const int k0 = t * PBK;
#pragma unroll
        for (int c = 0; c < 4; ++c) {
            const int ch = w * 4 + c;
            const int row = ch * 8 + rsub;
            glds16(Ag + (size_t)(ar0 + row) * HID + k0 + c16 * 8,
                   lds + buf * 16384 + ch * 1024);
            glds16(Bg + (size_t)(br0 + row) * HID + k0 + c16 * 8,
                   lds + 32768 + buf * 16384 + ch * 1024);
        }
    };

    stage(0, 0);
    f32x4 acc[4][4] = {};

    for (int t = 0; t < PNT; ++t) {
        asm volatile("s_waitcnt vmcnt(0)" ::: "memory");
        __builtin_amdgcn_s_barrier();
        __builtin_amdgcn_sched_barrier(0);
        if (t + 1 < PNT) stage(t + 1, (t + 1) & 1);
        const char* LA = lds + (t & 1) * 16384;
        const char* LB = lds + 32768 + (t & 1) * 16384;
#pragma unroll
        for (int ks = 0; ks < 2; ++ks) {
            bf16x8 af[4], bf_[4];
#pragma unroll
            for (int i = 0; i < 4; ++i) {
                const int rowA = wi * 64 + i * 16 + lr;
                af[i] = *reinterpret_cast<const bf16x8*>(
                    LA + rowA * 128 + (((ks * 4 + hi) ^ (rowA & 7)) << 4));
                const int rowB = wj * 64 + i * 16 + lr;
                bf_[i] = *reinterpret_cast<const bf16x8*>(
                    LB + rowB * 128 + (((ks * 4 + hi) ^ (rowB & 7)) << 4));
            }
            __builtin_amdgcn_s_setprio(1);
#pragma unroll
            for (int ia = 0; ia < 4; ++ia)
#pragma unroll
                for (int ib = 0; ib < 4; ++ib)
                    acc[ia][ib] = __builtin_amdgcn_mfma_f32_16x16x32_bf16(
                        af[ia], bf_[ib], acc[ia][ib], 0, 0, 0);
            __builtin_amdgcn_s_setprio(0);
        }
    }

    const float SCQ = 0.125f * 1.44269504088896340736f;
    if (z < 2) {
        short* outp = (z == 0) ? Qb : Kb;
        const float sc = (z == 0) ? SCQ : 1.0f;
#pragma unroll
        for (int ia = 0; ia < 4; ++ia) {
            const int nb = ar0 + wi * 64 + ia * 16 + hi * 4;
            const float4 b4 = *reinterpret_cast<const float4*>(bias + nb);
#pragma unroll
            for (int ib = 0; ib < 4; ++ib) {
                const int m = br0 + wj * 64 + ib * 16 + lr;
                s16x4 v;
                v[0] = f2bf((acc[ia][ib][0] + b4.x) * sc);
                v[1] = f2bf((acc[ia][ib][1] + b4.y) * sc);
                v[2] = f2bf((acc[ia][ib][2] + b4.z) * sc);
                v[3] = f2bf((acc[ia][ib][3] + b4.w) * sc);
                *reinterpret_cast<s16x4*>(outp + (size_t)m * HID + nb) = v;
            }
        }
    } else {
#pragma unroll
        for (int ib = 0; ib < 4; ++ib) {
            const int n = br0 + wj * 64 + ib * 16 + lr;
            const float bb = bias[n];
#pragma unroll
            for (int ia = 0; ia < 4; ++ia) {
                const int mb = ar0 + wi * 64 + ia * 16 + hi * 4;
                s16x4 v;
                v[0] = f2bf(acc[ia][ib][0] + bb);
                v[1] = f2bf(acc[ia][ib][1] + bb);
                v[2] = f2bf(acc[ia][ib][2] + bb);
                v[3] = f2bf(acc[ia][ib][3] + bb);
                *reinterpret_cast<s16x4*>(Vt + (size_t)n * SEQ + mb) = v;
            }
        }
    }
}

// ---------------------------------------------------------------------------
// Flash attention, KVB=128: 64q blocks, 8 waves = (qh 4) x (kh 2), each wave
// 16q x 64k per tile — 32 tiles => HALF the barrier/drain events of r13.
// Key-permuted QK^T (MFMA g -> keys kh*64+(g>>1)*32+(g&1)*4+hi*8+r) keeps
// P zero-shuffle (lane's 16 e's = its two PV B-fragments). Per-lane
// deferred-max softmax; mask*log2e f32 in LDS as MFMA C-init.
// LDS: K dbuf 2x16KB @0, V dbuf 2x16KB ([2kh][64][128B]) @32768,
//      mask f32 16KB @65536. 80KB -> 2 blocks/CU (16 waves).
// ---------------------------------------------------------------------------
__global__ __launch_bounds__(512, 4) void attn_kernel(
    const short* __restrict__ Qb, const short* __restrict__ Kb,
    const short* __restrict__ Vt, const float* __restrict__ maskp,
    float* __restrict__ out)
{
    __shared__ __align__(16) char lds[81920];
    const int tid  = threadIdx.x;
    const int lane = tid & 63;
    const int w    = tid >> 6;               // 0..7
    const int lr = lane & 15, hi = lane >> 4;
    const int qh = w >> 1, kh = w & 1;       // 4 q-groups x 2 key-halves
    const int head = blockIdx.y;
    const int q0 = blockIdx.x * 64 + qh * 16;
    const float ML = 1.44269504088896340736f;

    // ---- staging: wave w owns K chunks {w, w+8} and V chunks {w, w+8}
    // K tile [128 rows][128B] = 16 chunks; V tile [2kh][64][128B] = 16 chunks.
    const int srow = lane >> 3;
    const int c16k = (lane & 7) ^ srow ^ ((w & 1) << 2);   // same parity for w, w+8
    const int sofK0 = (w * 8 + srow) * HID + head * HDIM + c16k * 8;
    const int sofK1 = sofK0 + 64 * HID;
    const int sofV0 = (head * HDIM + (w & 7) * 8 + srow) * SEQ
                    + (w >> 3) * 64 + c16k * 8;            // cv = w (kh_v = w>>3 = 0)
    const int sofV1 = sofV0 + 64;                           // cv = w+8 (kh_v = 1)
    const short* gK = Kb;                       // advances by KVB*HID
    const short* gV = Vt;                       // advances by KVB
    char* sdK0 = lds + w * 1024;
    char* sdK1 = lds + (w + 8) * 1024;
    char* sdV0 = lds + 32768 + w * 1024;
    char* sdV1 = lds + 32768 + (w + 8) * 1024;

    auto stagep = [&](int buf) {
        const int bo = buf * 16384;
        glds16(gK + sofK0, sdK0 + bo);
        glds16(gK + sofK1, sdK1 + bo);
        glds16(gV + sofV0, sdV0 + bo);
        glds16(gV + sofV1, sdV1 + bo);
        gK += KVB * HID; gV += KVB;
    };

    stagep(0);   // tile 0 in flight across mask/Q staging

    // ---- stage mask*log2e as f32 (once): 4096 floats, 8 per thread
    {
        float* mb = (float*)(lds + 65536);
        const int base = tid * 8;
#pragma unroll
        for (int i = 0; i < 2; ++i) {
            float4 m4 = *reinterpret_cast<const float4*>(maskp + base + i * 4);
            m4.x *= ML; m4.y *= ML; m4.z *= ML; m4.w *= ML;
            *reinterpret_cast<float4*>(mb + base + i * 4) = m4;
        }
    }

    // ---- Q fragments (pre-scaled at projection): 16 q-rows, d 0..63
    const short* qp = Qb + (size_t)(q0 + lr) * HID + head * HDIM + hi * 8;
    const bf16x8 qf0 = *reinterpret_cast<const bf16x8*>(qp);
    const bf16x8 qf1 = *reinterpret_cast<const bf16x8*>(qp + 32);

    __syncthreads();   // mask + stage(0) visible to all waves

    // ---- K read pointers: base kp0 + immediate offsets; fr flips bit2
    // per (g&1) and swaps the two d-slots. rows = kh*64 + kbase + {0,4,32,36}.
    const int kbase = ((lr >> 2) * 8) + (lr & 3);          // a*8+b
    const int fr0   = (kbase & 7) ^ (((kbase >> 3) & 1) << 2);
    const char* kp0 = lds + (kh * 64 + kbase) * 128 + ((hi ^ fr0) << 4);
    // V read pointer: region kh, row lr (+dg*16), slot (hi^fv) (+^4 for j=1)
    const int fv    = (lr & 7) ^ (((lr >> 3) & 1) << 2);
    const char* vp0 = lds + 32768 + kh * 8192 + lr * 128 + ((hi ^ fv) << 4);
    const float* mptr = (const float*)(lds + 65536) + kh * 64 + hi * 8;

    f32x4 acc[4] = {};
    float m_r = -INFINITY, ls = 0.f;

    auto tile = [&](int tt, int buf) {
        asm volatile("s_waitcnt vmcnt(0)" ::: "memory");  // stage(tt) landed
        __builtin_amdgcn_s_barrier();
        __builtin_amdgcn_sched_barrier(0);
        if (tt + 1 < NT) stagep(buf ^ 1);

        // ---- C-init = mask*log2e at key offsets {0,4,32,36}+hi*8
        const f32x4 ci0 = *reinterpret_cast<const f32x4*>(mptr);
        const f32x4 ci1 = *reinterpret_cast<const f32x4*>(mptr + 4);
        const f32x4 ci2 = *reinterpret_cast<const f32x4*>(mptr + 32);
        const f32x4 ci3 = *reinterpret_cast<const f32x4*>(mptr + 36);
        mptr += KVB;

        // ---- QK^T (key-permuted): MFMA g -> keys (g>>1)*32+(g&1)*4+hi*8+r
        const int bo = buf * 16384;
        const char* kb = kp0 + bo;
        const bf16x8 k00 = *reinterpret_cast<const bf16x8*>(kb);
        const bf16x8 k01 = *reinterpret_cast<const bf16x8*>(
            (const char*)((size_t)kb ^ 64));
        const bf16x8 k10 = *reinterpret_cast<const bf16x8*>(
            (const char*)((size_t)(kb + 512) ^ 64));
        const bf16x8 k11 = *reinterpret_cast<const bf16x8*>(kb + 512);
        const bf16x8 k20 = *reinterpret_cast<const bf16x8*>(kb + 4096);
        const bf16x8 k21 = *reinterpret_cast<const bf16x8*>(
            (const char*)((size_t)(kb + 4096) ^ 64));
        const bf16x8 k30 = *reinterpret_cast<const bf16x8*>(
            (const char*)((size_t)(kb + 4608) ^ 64));
        const bf16x8 k31 = *reinterpret_cast<const bf16x8*>(kb + 4608);
        f32x4 z0 = ci0, z1 = ci1, z2 = ci2, z3 = ci3;
        __builtin_amdgcn_s_setprio(1);
        z0 = __builtin_amdgcn_mfma_f32_16x16x32_bf16(k00, qf0, z0, 0, 0, 0);
        z0 = __builtin_amdgcn_mfma_f32_16x16x32_bf16(k01, qf1, z0, 0, 0, 0);
        z1 = __builtin_amdgcn_mfma_f32_16x16x32_bf16(k10, qf0, z1, 0, 0, 0);
        z1 = __builtin_amdgcn_mfma_f32_16x16x32_bf16(k11, qf1, z1, 0, 0, 0);
        z2 = __builtin_amdgcn_mfma_f32_16x16x32_bf16(k20, qf0, z2, 0, 0, 0);
        z2 = __builtin_amdgcn_mfma_f32_16x16x32_bf16(k21, qf1, z2, 0, 0, 0);
        z3 = __builtin_amdgcn_mfma_f32_16x16x32_bf16(k30, qf0, z3, 0, 0, 0);
        z3 = __builtin_amdgcn_mfma_f32_16x16x32_bf16(k31, qf1, z3, 0, 0, 0);
        __builtin_amdgcn_s_setprio(0);

        // ---- e = exp2(z - m), per-lane (no cross-lane in common path)
        float e0[4], e1[4], e2[4], e3[4];
#pragma unroll
        for (int r = 0; r < 4; ++r) {
            e0[r] = exp2f(z0[r] - m_r);
            e1[r] = exp2f(z1[r] - m_r);
            e2[r] = exp2f(z2[r] - m_r);
            e3[r] = exp2f(z3[r] - m_r);
        }

        // ---- per-lane violation check: any e > 2^8?
        const float pa = max3f(e0[0], e0[1], e0[2]);
        const float pb = max3f(e0[3], e1[0], e1[1]);
        const float pc = max3f(e1[2], e1[3], e2[0]);
        const float pd = max3f(e2[1], e2[2], e2[3]);
        const float pe = max3f(e3[0], e3[1], e3[2]);
        const float pmax = max3f(fmaxf(pa, pb), fmaxf(pc, pd),
                                 fmaxf(pe, e3[3]));
        if (__ballot(pmax > 256.f)) {
            // rare recovery: full cross-lane max over this q-row's 64 keys
            float t_ = fmaxf(
                fmaxf(max3f(z0[0], z0[1], z0[2]),
                      max3f(z0[3], z1[0], z1[1])),
                fmaxf(max3f(z1[2], z1[3], z2[0]),
                      fmaxf(max3f(z2[1], z2[2], z2[3]),
                            fmaxf(max3f(z3[0], z3[1], z3[2]), z3[3]))));
            t_ = fmaxf(t_, __shfl_xor(t_, 16));
            t_ = fmaxf(t_, __shfl_xor(t_, 32));
            const float newm = fmaxf(m_r, t_);
            const float sc = exp2f(fmaxf(m_r - newm, -128.f));
            ls *= sc;
#pragma unroll
            for (int dg = 0; dg < 4; ++dg) acc[dg] *= sc;
            m_r = newm;
#pragma unroll
            for (int r = 0; r < 4; ++r) {
                e0[r] = exp2f(z0[r] - newm);
                e1[r] = exp2f(z1[r] - newm);
                e2[r] = exp2f(z2[r] - newm);
                e3[r] = exp2f(z3[r] - newm);
            }
        }

        // ---- accumulate l, pack P (zero-shuffle: e's ARE the PV B-frags)
        ls += (((e0[0] + e0[1]) + (e0[2] + e0[3]))
             + ((e1[0] + e1[1]) + (e1[2] + e1[3])))
            + (((e2[0] + e2[1]) + (e2[2] + e2[3]))
             + ((e3[0] + e3[1]) + (e3[2] + e3[3])));
        union { unsigned u[4]; bf16x8 v; } P0, P1;
        P0.u[0] = cvtpk(e0[0], e0[1]); P0.u[1] = cvtpk(e0[2], e0[3]);
        P0.u[2] = cvtpk(e1[0], e1[1]); P0.u[3] = cvtpk(e1[2], e1[3]);
        P1.u[0] = cvtpk(e2[0], e2[1]); P1.u[1] = cvtpk(e2[2], e2[3]);
        P1.u[2] = cvtpk(e3[0], e3[1]); P1.u[3] = cvtpk(e3[2], e3[3]);

        // ---- PV: O[d][q] += V[d][k]·P[k][q], 2 j-frags x 4 dg
        const char* vb = vp0 + bo;
        __builtin_amdgcn_s_setprio(1);
#pragma unroll
        for (int dg = 0; dg < 4; ++dg) {
            const bf16x8 vf0 = *reinterpret_cast<const bf16x8*>(vb + dg * 2048);
            const bf16x8 vf1 = *reinterpret_cast<const bf16x8*>(
                (const char*)((size_t)(vb + dg * 2048) ^ 64));
            acc[dg] = __builtin_amdgcn_mfma_f32_16x16x32_bf16(vf0, P0.v, acc[dg], 0, 0, 0);
            acc[dg] = __builtin_amdgcn_mfma_f32_16x16x32_bf16(vf1, P1.v, acc[dg], 0, 0, 0);
        }
        __builtin_amdgcn_s_setprio(0);
    };

#pragma unroll 1
    for (int t = 0; t < NT; t += 2) {
        tile(t, 0);
        tile(t + 1, 1);
    }

    // ---- reduce l across hi-groups
    ls += __shfl_xor(ls, 16);
    ls += __shfl_xor(ls, 32);

    // ---- flash-merge the two key-halves through LDS (overlay K buffers)
    __syncthreads();
    float* mg  = (float*)lds;                 // [qh][dg][lane] f32x4 = 16KB
    float* mlb = (float*)(lds + 16384);       // [qh][lane] float2 = 2KB
    if (kh == 1) {
        float2 v0; v0.x = m_r; v0.y = ls;
        *reinterpret_cast<float2*>(mlb + (qh * 64 + lane) * 2) = v0;
#pragma unroll
        for (int dg = 0; dg < 4; ++dg)
            *reinterpret_cast<f32x4*>(
                mg + ((qh * 4 + dg) * 64 + lane) * 4) = acc[dg];
    }
    __syncthreads();
    if (kh == 0) {
        const float2 v = *reinterpret_cast<const float2*>(
            mlb + (qh * 64 + lane) * 2);
        const float mm = fmaxf(m_r, v.x);
        const float sc0 = exp2f(fmaxf(m_r - mm, -128.f));
        const float sc1 = exp2f(fmaxf(v.x - mm, -128.f));
        const float rl = 1.0f / (ls * sc0 + v.y * sc1);
#pragma unroll
        for (int dg = 0; dg < 4; ++dg) {
            const f32x4 o1v = *reinterpret_cast<const f32x4*>(
                mg + ((qh * 4 + dg) * 64 + lane) * 4);
            const f32x4 of = (acc[dg] * sc0 + o1v * sc1) * rl;
            float* op = out + (size_t)(q0 + lr) * HID
                      + head * HDIM + dg * 16 + hi * 4;
            *reinterpret_cast<f32x4*>(op) = of;
        }
    }
}

// ---------------------------------------------------------------------------
extern "C" void kernel_launch(void* const* d_in, const int* in_sizes, int n_in,
                              void* d_out, int out_size, void* d_ws, size_t ws_size,
                              hipStream_t stream) {
    const float* hs   = (const float*)d_in[0];
    const float* mask = (const float*)d_in[1];
    const float* Wq   = (const float*)d_in[2];
    const float* bq   = (const float*)d_in[3];
    const float* Wk   = (const float*)d_in[4];
    const float* bk   = (const float*)d_in[5];
    const float* Wv   = (const float*)d_in[6];
    const float* bv   = (const float*)d_in[7];

    short* Qb = (short*)d_ws;                       // bf16 [SEQ][HID], pre-scaled
    short* Kb = Qb + (size_t)SEQ * HID;             // bf16 [SEQ][HID]
    short* Vt = Kb + (size_t)SEQ * HID;             // bf16 [HID][SEQ]
    float* out = (float*)d_out;

    // bf16 scratch carved from d_out (attn overwrites it at the very end)
    short* hsb = (short*)d_out;
    short* Wb  = hsb + (size_t)SEQ * HID;

    cast_bf16_kernel<<<dim3(SEQ * HID / 2048), 256, 0, stream>>>(hs, hsb);
    cast_w_kernel<<<dim3(HID * HID / 2048, 3), 256, 0, stream>>>(Wq, Wk, Wv, Wb);

    qkv_proj_kernel<<<dim3(HID / 128, SEQ / 128, 3), 256, 0, stream>>>(
        hsb, Wb, bq, bk, bv, Qb, Kb, Vt);

    attn_kernel<<<dim3(SEQ / 64, NHEAD), 512, 0, stream>>>(Qb, Kb, Vt, mask, out);
}

// Round 15
// 135.352 us; speedup vs baseline: 1.2261x; 1.2261x over previous
//
#include <hip/hip_runtime.h>
#include <hip/hip_bf16.h>

#define SEQ 4096
#define HID 768
#define NHEAD 12
#define HDIM 64
#define KVB 64
#define NT (SEQ / KVB)   // 64
#define PBK 64
#define PNT (HID / PBK)  // 12

typedef __attribute__((ext_vector_type(8))) short bf16x8;
typedef __attribute__((ext_vector_type(4))) float f32x4;
typedef __attribute__((ext_vector_type(4))) short s16x4;

static __device__ __forceinline__ short f2bf(float f) {
    unsigned u = __builtin_bit_cast(unsigned, f);
    unsigned r = (u + 0x7fffu + ((u >> 16) & 1u)) >> 16;
    return (short)r;
}
static __device__ __forceinline__ unsigned cvtpk(float lo, float hi) {
    unsigned r;
    asm("v_cvt_pk_bf16_f32 %0, %1, %2" : "=v"(r) : "v"(lo), "v"(hi));
    return r;
}
static __device__ __forceinline__ float max3f(float a, float b, float c) {
    float r;
    asm("v_max3_f32 %0, %1, %2, %3" : "=v"(r) : "v"(a), "v"(b), "v"(c));
    return r;
}
static __device__ __forceinline__ void glds16(const void* g, void* l) {
    __builtin_amdgcn_global_load_lds(
        (const __attribute__((address_space(1))) unsigned*)g,
        (__attribute__((address_space(3))) unsigned*)l, 16, 0, 0);
}

// ---------------------------------------------------------------------------
// Merged fp32 -> bf16 cast for hs + Wq/Wk/Wv (one launch).
// Unit = 8 elements. hs: 393216 units; each W: 73728 units. Grid 2400x256.
// ---------------------------------------------------------------------------
__global__ __launch_bounds__(256) void cast_all_kernel(
    const float* __restrict__ hs, const float* __restrict__ Wq,
    const float* __restrict__ Wk, const float* __restrict__ Wv,
    short* __restrict__ hsb, short* __restrict__ Wb)
{
    const size_t i = (size_t)blockIdx.x * 256 + threadIdx.x;
    const float* s; short* d; size_t idx;
    if (i < 393216) {
        s = hs; d = hsb; idx = i;
    } else {
        size_t j = i - 393216;
        int z = (int)(j / 73728);
        idx = j - (size_t)z * 73728;
        s = (z == 0) ? Wq : ((z == 1) ? Wk : Wv);
        d = Wb + (size_t)z * HID * HID;
    }
    const float4* sp = reinterpret_cast<const float4*>(s) + idx * 2;
    const float4 a = sp[0], b = sp[1];
    bf16x8 o;
    o[0] = f2bf(a.x); o[1] = f2bf(a.y); o[2] = f2bf(a.z); o[3] = f2bf(a.w);
    o[4] = f2bf(b.x); o[5] = f2bf(b.y); o[6] = f2bf(b.z); o[7] = f2bf(b.w);
    reinterpret_cast<bf16x8*>(d)[idx] = o;
}

// ---------------------------------------------------------------------------
// QKV projection, LDS-staged. Tile 128x128, BK=64, dbuf 64KB.
// Q output pre-scaled by 0.125*log2e (folds the softmax scale).
// ---------------------------------------------------------------------------
__global__ __launch_bounds__(256) void qkv_proj_kernel(
    const short* __restrict__ hsb, const short* __restrict__ Wb,
    const float* __restrict__ bq, const float* __restrict__ bk,
    const float* __restrict__ bv,
    short* __restrict__ Qb, short* __restrict__ Kb, short* __restrict__ Vt)
{
    __shared__ __align__(16) char lds[65536];
    const int z = blockIdx.z;
    const float* bias = (z == 0) ? bq : ((z == 1) ? bk : bv);

    const int lane = threadIdx.x & 63;
    const int w    = threadIdx.x >> 6;
    const int lr = lane & 15, hi = lane >> 4;
    const int wi = w >> 1, wj = w & 1;

    const short* Ag; const short* Bg; int ar0, br0;
    if (z < 2) { Ag = Wb + (size_t)z * HID * HID; ar0 = blockIdx.x * 128;
                 Bg = hsb;                        br0 = blockIdx.y * 128; }
    else       { Ag = hsb;                        ar0 = blockIdx.y * 128;
                 Bg = Wb + (size_t)2 * HID * HID; br0 = blockIdx.x * 128; }

    const int rsub = lane >> 3;
    const int c16  = (lane & 7) ^ rsub;

    auto stage = [&](int t, int buf) {
        const int k0 = t * PBK;
#pragma unroll
        for (int c = 0; c < 4; ++c) {
            const int ch = w * 4 + c;
            const int row = ch * 8 + rsub;
            glds16(Ag + (size_t)(ar0 + row) * HID + k0 + c16 * 8,
                   lds + buf * 16384 + ch * 1024);
            glds16(Bg + (size_t)(br0 + row) * HID + k0 + c16 * 8,
                   lds + 32768 + buf * 16384 + ch * 1024);
        }
    };

    stage(0, 0);
    f32x4 acc[4][4] = {};

    for (int t = 0; t < PNT; ++t) {
        asm volatile("s_waitcnt vmcnt(0)" ::: "memory");
        __builtin_amdgcn_s_barrier();
        __builtin_amdgcn_sched_barrier(0);
        if (t + 1 < PNT) stage(t + 1, (t + 1) & 1);
        const char* LA = lds + (t & 1) * 16384;
        const char* LB = lds + 32768 + (t & 1) * 16384;
#pragma unroll
        for (int ks = 0; ks < 2; ++ks) {
            bf16x8 af[4], bf_[4];
#pragma unroll
            for (int i = 0; i < 4; ++i) {
                const int rowA = wi * 64 + i * 16 + lr;
                af[i] = *reinterpret_cast<const bf16x8*>(
                    LA + rowA * 128 + (((ks * 4 + hi) ^ (rowA & 7)) << 4));
                const int rowB = wj * 64 + i * 16 + lr;
                bf_[i] = *reinterpret_cast<const bf16x8*>(
                    LB + rowB * 128 + (((ks * 4 + hi) ^ (rowB & 7)) << 4));
            }
            __builtin_amdgcn_s_setprio(1);
#pragma unroll
            for (int ia = 0; ia < 4; ++ia)
#pragma unroll
                for (int ib = 0; ib < 4; ++ib)
                    acc[ia][ib] = __builtin_amdgcn_mfma_f32_16x16x32_bf16(
                        af[ia], bf_[ib], acc[ia][ib], 0, 0, 0);
            __builtin_amdgcn_s_setprio(0);
        }
    }

    const float SCQ = 0.125f * 1.44269504088896340736f;
    if (z < 2) {
        short* outp = (z == 0) ? Qb : Kb;
        const float sc = (z == 0) ? SCQ : 1.0f;
#pragma unroll
        for (int ia = 0; ia < 4; ++ia) {
            const int nb = ar0 + wi * 64 + ia * 16 + hi * 4;
            const float4 b4 = *reinterpret_cast<const float4*>(bias + nb);
#pragma unroll
            for (int ib = 0; ib < 4; ++ib) {
                const int m = br0 + wj * 64 + ib * 16 + lr;
                s16x4 v;
                v[0] = f2bf((acc[ia][ib][0] + b4.x) * sc);
                v[1] = f2bf((acc[ia][ib][1] + b4.y) * sc);
                v[2] = f2bf((acc[ia][ib][2] + b4.z) * sc);
                v[3] = f2bf((acc[ia][ib][3] + b4.w) * sc);
                *reinterpret_cast<s16x4*>(outp + (size_t)m * HID + nb) = v;
            }
        }
    } else {
#pragma unroll
        for (int ib = 0; ib < 4; ++ib) {
            const int n = br0 + wj * 64 + ib * 16 + lr;
            const float bb = bias[n];
#pragma unroll
            for (int ia = 0; ia < 4; ++ia) {
                const int mb = ar0 + wi * 64 + ia * 16 + hi * 4;
                s16x4 v;
                v[0] = f2bf(acc[ia][ib][0] + bb);
                v[1] = f2bf(acc[ia][ib][1] + bb);
                v[2] = f2bf(acc[ia][ib][2] + bb);
                v[3] = f2bf(acc[ia][ib][3] + bb);
                *reinterpret_cast<s16x4*>(Vt + (size_t)n * SEQ + mb) = v;
            }
        }
    }
}

// ---------------------------------------------------------------------------
// Flash attention (r13 geometry + T15 deferred-PV pipeline): 64q blocks,
// 8 waves = (qh 4) x (kh 2), each wave 16q x 32k per tile. Window t issues
// QK(t) MFMAs AND PV(t-1) MFMAs back-to-back, then softmax(t) runs as pure
// VALU that nothing in this window waits on — breaks the lockstep convoy.
// V ring = 4 buffers (PV reads one window behind the stager); K dbuf = 2.
// P_prev in registers; t=0 uses P_prev=0 + zeroed V[3] (NaN-safe).
// Zero-shuffle P via key-permuted QK^T; per-lane deferred-max softmax;
// mask*log2e f32 in LDS as MFMA C-init.
// LDS: K 2x8KB @0, V 4x8KB @16384, mask f32 16KB @49152. 64KB -> 2 blk/CU.
// ---------------------------------------------------------------------------
__global__ __launch_bounds__(512, 4) void attn_kernel(
    const short* __restrict__ Qb, const short* __restrict__ Kb,
    const short* __restrict__ Vt, const float* __restrict__ maskp,
    float* __restrict__ out)
{
    __shared__ __align__(16) char lds[65536];
    const int tid  = threadIdx.x;
    const int lane = tid & 63;
    const int w    = tid >> 6;               // 0..7
    const int lr = lane & 15, hi = lane >> 4;
    const int qh = w >> 1, kh = w & 1;       // 4 q-groups x 2 key-halves
    const int head = blockIdx.y;
    const int q0 = blockIdx.x * 64 + qh * 16;
    const float ML = 1.44269504088896340736f;

    // ---- staging: wave w owns K-chunk w and V-chunk w (8 rows x 128B each)
    const int srow = lane >> 3;
    const int c16s = (lane & 7) ^ srow ^ ((w & 1) << 2);
    const int sofK = (w * 8 + srow) * HID + head * HDIM + c16s * 8;
    const int sofV = (head * HDIM + w * 8 + srow) * SEQ + c16s * 8;
    const short* gK = Kb;                       // advances by KVB*HID
    const short* gV = Vt;                       // advances by KVB
    char* sdK = lds + w * 1024;
    char* sdV = lds + 16384 + w * 1024;

    auto stagep = [&](int kb, int vb) {
        glds16(gK + sofK, sdK + kb * 8192);
        glds16(gV + sofV, sdV + vb * 8192);
        gK += KVB * HID; gV += KVB;
    };

    stagep(0, 0);   // tile 0 in flight across mask/Q staging

    // ---- stage mask*log2e as f32 (once): 4096 floats, 8 per thread
    {
        float* mb = (float*)(lds + 49152);
        const int base = tid * 8;
#pragma unroll
        for (int i = 0; i < 2; ++i) {
            float4 m4 = *reinterpret_cast<const float4*>(maskp + base + i * 4);
            m4.x *= ML; m4.y *= ML; m4.z *= ML; m4.w *= ML;
            *reinterpret_cast<float4*>(mb + base + i * 4) = m4;
        }
    }

    // ---- zero V buffer 3 (read by the t=0 dummy PV; NaN-safety)
    {
        f32x4 zz = {};
        *reinterpret_cast<f32x4*>(lds + 16384 + 3 * 8192 + w * 1024 + lane * 16) = zz;
    }

    // ---- Q fragments (pre-scaled by 0.125*log2e at projection): 16 q-rows
    const short* qp = Qb + (size_t)(q0 + lr) * HID + head * HDIM + hi * 8;
    const bf16x8 qf0 = *reinterpret_cast<const bf16x8*>(qp);
    const bf16x8 qf1 = *reinterpret_cast<const bf16x8*>(qp + 32);

    __syncthreads();   // mask + V3-zero + stage(0) visible to all waves

    // ---- K read pointers: 2 VGPR bases + immediate offsets (r13 layout)
    const int kbase = ((lr >> 2) * 8) + (lr & 3);
    const int krow0 = kh * 32 + kbase;
    const int fr0   = (krow0 & 7) ^ (((krow0 >> 3) & 1) << 2);
    const int o1    = (hi ^ fr0) << 4;
    const char* kpA = lds + krow0 * 128 + o1;
    const char* kpB = lds + krow0 * 128 + (o1 ^ 64);
    const int fv    = (lr & 7) ^ (((lr >> 3) & 1) << 2);
    const char* vpB = lds + 16384 + lr * 128 + (((kh * 4 + hi) ^ fv) << 4);
    const float* mptr = (const float*)(lds + 49152) + kh * 32 + hi * 8;

    f32x4 acc[4] = {};
    float m_r = -INFINITY, ls = 0.f;
    union { unsigned u[4]; bf16x8 v; } Pp;     // deferred P (previous tile)
    Pp.u[0] = 0; Pp.u[1] = 0; Pp.u[2] = 0; Pp.u[3] = 0;

    auto tile = [&](int tt, int kb, int vbn, int vbp) {
        asm volatile("s_waitcnt vmcnt(0)" ::: "memory");  // stage(tt) landed
        __builtin_amdgcn_s_barrier();
        __builtin_amdgcn_sched_barrier(0);
        if (tt + 1 < NT) stagep(kb ^ 1, vbn);

        // ---- QK^T (key-permuted) C-init = mask*log2e, then PV(t-1):
        // one back-to-back MFMA cluster; softmax below depends only on z.
        const f32x4 ci0 = *reinterpret_cast<const f32x4*>(mptr);
        const f32x4 ci1 = *reinterpret_cast<const f32x4*>(mptr + 4);
        mptr += KVB;
        const int bo = kb * 8192;
        const bf16x8 kf00 = *reinterpret_cast<const bf16x8*>(kpA + bo);
        const bf16x8 kf01 = *reinterpret_cast<const bf16x8*>(kpB + bo);
        const bf16x8 kf10 = *reinterpret_cast<const bf16x8*>(kpB + bo + 512);
        const bf16x8 kf11 = *reinterpret_cast<const bf16x8*>(kpA + bo + 512);
        f32x4 z0 = ci0, z1 = ci1;
        const char* vb = vpB + vbp * 8192;
        __builtin_amdgcn_s_setprio(1);
        z0 = __builtin_amdgcn_mfma_f32_16x16x32_bf16(kf00, qf0, z0, 0, 0, 0);
        z0 = __builtin_amdgcn_mfma_f32_16x16x32_bf16(kf01, qf1, z0, 0, 0, 0);
        z1 = __builtin_amdgcn_mfma_f32_16x16x32_bf16(kf10, qf0, z1, 0, 0, 0);
        z1 = __builtin_amdgcn_mfma_f32_16x16x32_bf16(kf11, qf1, z1, 0, 0, 0);
#pragma unroll
        for (int dg = 0; dg < 4; ++dg) {
            const bf16x8 vf = *reinterpret_cast<const bf16x8*>(vb + dg * 2048);
            acc[dg] = __builtin_amdgcn_mfma_f32_16x16x32_bf16(vf, Pp.v, acc[dg], 0, 0, 0);
        }
        __builtin_amdgcn_s_setprio(0);

        // ---- e = exp2(z - m), per-lane (no cross-lane ops in common path)
        float e0[4], e1[4];
#pragma unroll
        for (int r = 0; r < 4; ++r) {
            e0[r] = exp2f(z0[r] - m_r);
            e1[r] = exp2f(z1[r] - m_r);
        }

        // ---- per-lane violation check: any e > 2^8?
        const float pa = max3f(e0[0], e0[1], e0[2]);
        const float pb = max3f(e0[3], e1[0], e1[1]);
        const float pc = max3f(e1[2], e1[3], pa);
        const float pmax = fmaxf(pb, pc);
        if (__ballot(pmax > 256.f)) {
            // rare recovery: full cross-lane max over this q-row's 32 keys.
            // acc already contains PV(t-1), so the rescale is exact.
            float t_ = fmaxf(
                max3f(z0[0], z0[1], z0[2]),
                max3f(fmaxf(z0[3], z1[0]), fmaxf(z1[1], z1[2]), z1[3]));
            t_ = fmaxf(t_, __shfl_xor(t_, 16));
            t_ = fmaxf(t_, __shfl_xor(t_, 32));
            const float newm = fmaxf(m_r, t_);
            const float sc = exp2f(fmaxf(m_r - newm, -128.f));
            ls *= sc;
#pragma unroll
            for (int dg = 0; dg < 4; ++dg) acc[dg] *= sc;
            m_r = newm;
#pragma unroll
            for (int r = 0; r < 4; ++r) {
                e0[r] = exp2f(z0[r] - newm);
                e1[r] = exp2f(z1[r] - newm);
            }
        }

        // ---- accumulate l, pack P for NEXT window's PV (zero-shuffle)
        ls += ((e0[0] + e0[1]) + (e0[2] + e0[3]))
            + ((e1[0] + e1[1]) + (e1[2] + e1[3]));
        Pp.u[0] = cvtpk(e0[0], e0[1]);
        Pp.u[1] = cvtpk(e0[2], e0[3]);
        Pp.u[2] = cvtpk(e1[0], e1[1]);
        Pp.u[3] = cvtpk(e1[2], e1[3]);
    };

#pragma unroll 1
    for (int t = 0; t < NT; t += 4) {
        tile(t,     0, 1, 3);
        tile(t + 1, 1, 2, 0);
        tile(t + 2, 0, 3, 1);
        tile(t + 3, 1, 0, 2);
    }

    // ---- epilogue: PV for the last tile (V[63&3] = V[3], still resident)
    {
        const char* vb = vpB + 3 * 8192;
        __builtin_amdgcn_s_setprio(1);
#pragma unroll
        for (int dg = 0; dg < 4; ++dg) {
            const bf16x8 vf = *reinterpret_cast<const bf16x8*>(vb + dg * 2048);
            acc[dg] = __builtin_amdgcn_mfma_f32_16x16x32_bf16(vf, Pp.v, acc[dg], 0, 0, 0);
        }
        __builtin_amdgcn_s_setprio(0);
    }

    // ---- reduce l across hi-groups
    ls += __shfl_xor(ls, 16);
    ls += __shfl_xor(ls, 32);

    // ---- flash-merge the two key-halves through LDS (overlay K/V buffers)
    __syncthreads();
    float* mg  = (float*)lds;                 // [qh][dg][lane] f32x4 = 16KB
    float* mlb = (float*)(lds + 16384);       // [qh][lane] float2 = 2KB
    if (kh == 1) {
        float2 v0; v0.x = m_r; v0.y = ls;
        *reinterpret_cast<float2*>(mlb + (qh * 64 + lane) * 2) = v0;
#pragma unroll
        for (int dg = 0; dg < 4; ++dg)
            *reinterpret_cast<f32x4*>(
                mg + ((qh * 4 + dg) * 64 + lane) * 4) = acc[dg];
    }
    __syncthreads();
    if (kh == 0) {
        const float2 v = *reinterpret_cast<const float2*>(
            mlb + (qh * 64 + lane) * 2);
        const float mm = fmaxf(m_r, v.x);
        const float sc0 = exp2f(fmaxf(m_r - mm, -128.f));
        const float sc1 = exp2f(fmaxf(v.x - mm, -128.f));
        const float rl = 1.0f / (ls * sc0 + v.y * sc1);
#pragma unroll
        for (int dg = 0; dg < 4; ++dg) {
            const f32x4 o1v = *reinterpret_cast<const f32x4*>(
                mg + ((qh * 4 + dg) * 64 + lane) * 4);
            const f32x4 of = (acc[dg] * sc0 + o1v * sc1) * rl;
            float* op = out + (size_t)(q0 + lr) * HID
                      + head * HDIM + dg * 16 + hi * 4;
            *reinterpret_cast<f32x4*>(op) = of;
        }
    }
}

// ---------------------------------------------------------------------------
extern "C" void kernel_launch(void* const* d_in, const int* in_sizes, int n_in,
                              void* d_out, int out_size, void* d_ws, size_t ws_size,
                              hipStream_t stream) {
    const float* hs   = (const float*)d_in[0];
    const float* mask = (const float*)d_in[1];
    const float* Wq   = (const float*)d_in[2];
    const float* bq   = (const float*)d_in[3];
    const float* Wk   = (const float*)d_in[4];
    const float* bk   = (const float*)d_in[5];
    const float* Wv   = (const float*)d_in[6];
    const float* bv   = (const float*)d_in[7];

    short* Qb = (short*)d_ws;                       // bf16 [SEQ][HID], pre-scaled
    short* Kb = Qb + (size_t)SEQ * HID;             // bf16 [SEQ][HID]
    short* Vt = Kb + (size_t)SEQ * HID;             // bf16 [HID][SEQ]
    float* out = (float*)d_out;

    // bf16 scratch carved from d_out (attn overwrites it at the very end)
    short* hsb = (short*)d_out;
    short* Wb  = hsb + (size_t)SEQ * HID;

    cast_all_kernel<<<dim3(2400), 256, 0, stream>>>(hs, Wq, Wk, Wv, hsb, Wb);

    qkv_proj_kernel<<<dim3(HID / 128, SEQ / 128, 3), 256, 0, stream>>>(
        hsb, Wb, bq, bk, bv, Qb, Kb, Vt);

    attn_kernel<<<dim3(SEQ / KVB, NHEAD), 512, 0, stream>>>(Qb, Kb, Vt, mask, out);
}